// Round 1
// baseline (185.359 us; speedup 1.0000x reference)
//
#include <hip/hip_runtime.h>
#include <stdint.h>

#define MARGIN 0.3f
#define M 1024
#define NG 32768
#define K 512
#define BM 128
#define BN 128
#define BK 64
#define NT (NG / BN)    // 256 n-tiles
#define NPART (NT * 2)  // 512 partials per row (2 waves per n-tile)

typedef __attribute__((ext_vector_type(8))) __bf16 bf16x8;
typedef __attribute__((ext_vector_type(4))) float f32x4;
typedef unsigned short ushort_t;
typedef unsigned int uint_t;

// ---- f32 -> bf16 (RNE) ----
static __device__ __forceinline__ ushort_t f2bf(float f) {
    uint_t u = __float_as_uint(f);
    u += 0x7FFFu + ((u >> 16) & 1u);
    return (ushort_t)(u >> 16);
}

__global__ __launch_bounds__(256) void cvt_kernel(const float* __restrict__ src,
                                                  ushort_t* __restrict__ dst, int n8) {
    int i = blockIdx.x * 256 + threadIdx.x;
    if (i >= n8) return;
    const float4* s4 = (const float4*)src;
    float4 a = s4[2 * i];
    float4 b = s4[2 * i + 1];
    uint4 o;
    o.x = (uint_t)f2bf(a.x) | ((uint_t)f2bf(a.y) << 16);
    o.y = (uint_t)f2bf(a.z) | ((uint_t)f2bf(a.w) << 16);
    o.z = (uint_t)f2bf(b.x) | ((uint_t)f2bf(b.y) << 16);
    o.w = (uint_t)f2bf(b.z) | ((uint_t)f2bf(b.w) << 16);
    ((uint4*)dst)[i] = o;
}

// ---- async global->LDS, 16B per lane ----
static __device__ __forceinline__ void gload_lds16(const void* gptr, void* lptr) {
    __builtin_amdgcn_global_load_lds(
        (const __attribute__((address_space(1))) uint32_t*)(gptr),
        (__attribute__((address_space(3))) uint32_t*)(uintptr_t)(lptr),
        16, 0, 0);
}

// ---- fused GEMM + masked min/max partial reduction ----
__global__ __launch_bounds__(256) void gemm_kernel(
    const ushort_t* __restrict__ A,   // [1024][512] bf16
    const ushort_t* __restrict__ B,   // [32768][512] bf16
    const int* __restrict__ targets,  // [1024]
    const int* __restrict__ idxv,     // [1024]
    const int* __restrict__ labels,   // [32768]
    float* __restrict__ pos_part,     // [1024][NPART]
    float* __restrict__ neg_part) {   // [1024][NPART]

    __shared__ __align__(16) ushort_t sA[BM * BK];
    __shared__ __align__(16) ushort_t sB[BN * BK];
    __shared__ int t_s[BM];
    __shared__ int i_s[BM];
    __shared__ int l_s[BN];

    const int tid = threadIdx.x;
    const int lane = tid & 63;
    const int w = tid >> 6;       // wave 0..3
    const int wm = w >> 1;        // 0..1 (row half)
    const int wn = w & 1;         // 0..1 (col half)
    const int bid = blockIdx.x;
    const int mtile = bid & 7;    // 8 consecutive blocks share a B panel
    const int ntile = bid >> 3;

    if (tid < BM) {
        t_s[tid] = targets[mtile * BM + tid];
        i_s[tid] = idxv[mtile * BM + tid];
    } else {
        l_s[tid - BM] = labels[ntile * BN + (tid - BM)];
    }

    f32x4 zero = {0.f, 0.f, 0.f, 0.f};
    f32x4 acc[4][4];
#pragma unroll
    for (int a = 0; a < 4; ++a)
#pragma unroll
        for (int b = 0; b < 4; ++b) acc[a][b] = zero;

    const int lrow8 = lane >> 3;        // 0..7
    const int lcol = (lane & 7) * 8;    // element col, 16B per lane

#pragma unroll 1
    for (int kt = 0; kt < K / BK; ++kt) {
        const int kk = kt * BK;
        // stage A and B tiles: 16 chunks of 1KB each per tensor, chunk c = i*4 + w
#pragma unroll
        for (int i = 0; i < 4; ++i) {
            const int c = i * 4 + w;
            const int row = c * 8 + lrow8;
            gload_lds16(&A[(size_t)(mtile * BM + row) * K + kk + lcol], &sA[c * 512]);
            gload_lds16(&B[(size_t)(ntile * BN + row) * K + kk + lcol], &sB[c * 512]);
        }
        __syncthreads();
#pragma unroll
        for (int k2 = 0; k2 < 2; ++k2) {
            bf16x8 av[4], bv[4];
#pragma unroll
            for (int mf = 0; mf < 4; ++mf)
                av[mf] = *(const bf16x8*)&sA[(wm * 64 + mf * 16 + (lane & 15)) * BK + k2 * 32 + (lane >> 4) * 8];
#pragma unroll
            for (int nf = 0; nf < 4; ++nf)
                bv[nf] = *(const bf16x8*)&sB[(wn * 64 + nf * 16 + (lane & 15)) * BK + k2 * 32 + (lane >> 4) * 8];
#pragma unroll
            for (int mf = 0; mf < 4; ++mf)
#pragma unroll
                for (int nf = 0; nf < 4; ++nf)
                    acc[mf][nf] = __builtin_amdgcn_mfma_f32_16x16x32_bf16(av[mf], bv[nf], acc[mf][nf], 0, 0, 0);
        }
        __syncthreads();
    }

    // ---- epilogue: masked min/max over this block's 64-col wave stripe ----
    const int l15 = lane & 15;
    const int lhi = lane >> 4;
    int labv[4], jv[4];
#pragma unroll
    for (int nf = 0; nf < 4; ++nf) {
        const int cl = wn * 64 + nf * 16 + l15;
        labv[nf] = l_s[cl];
        jv[nf] = ntile * BN + cl;
    }
#pragma unroll
    for (int mf = 0; mf < 4; ++mf) {
#pragma unroll
        for (int r = 0; r < 4; ++r) {
            const int row_l = wm * 64 + mf * 16 + lhi * 4 + r;
            const int tgt = t_s[row_l];
            const int exc = i_s[row_l];
            float pmin = INFINITY, nmax = -INFINITY;
#pragma unroll
            for (int nf = 0; nf < 4; ++nf) {
                const float v = acc[mf][nf][r];
                const bool same = (labv[nf] == tgt);
                pmin = fminf(pmin, (same && (jv[nf] != exc)) ? v : INFINITY);
                nmax = fmaxf(nmax, same ? -INFINITY : v);
            }
#pragma unroll
            for (int s = 1; s < 16; s <<= 1) {
                pmin = fminf(pmin, __shfl_xor(pmin, s, 64));
                nmax = fmaxf(nmax, __shfl_xor(nmax, s, 64));
            }
            if (l15 == 0) {
                const int row_g = mtile * BM + row_l;
                pos_part[(size_t)row_g * NPART + ntile * 2 + wn] = pmin;
                neg_part[(size_t)row_g * NPART + ntile * 2 + wn] = nmax;
            }
        }
    }
}

// ---- per-row reduce of partials -> hinge loss ----
__global__ __launch_bounds__(256) void rowred_kernel(const float* __restrict__ pos_part,
                                                     const float* __restrict__ neg_part,
                                                     float* __restrict__ loss) {
    const int row = blockIdx.x;
    const int t = threadIdx.x;
    const float* pp = pos_part + (size_t)row * NPART;
    const float* nn = neg_part + (size_t)row * NPART;
    float p = fminf(pp[t], pp[t + 256]);
    float nx = fmaxf(nn[t], nn[t + 256]);
#pragma unroll
    for (int s = 1; s < 64; s <<= 1) {
        p = fminf(p, __shfl_xor(p, s, 64));
        nx = fmaxf(nx, __shfl_xor(nx, s, 64));
    }
    __shared__ float sp[4], sn[4];
    if ((t & 63) == 0) { sp[t >> 6] = p; sn[t >> 6] = nx; }
    __syncthreads();
    if (t == 0) {
        p = fminf(fminf(sp[0], sp[1]), fminf(sp[2], sp[3]));
        nx = fmaxf(fmaxf(sn[0], sn[1]), fmaxf(sn[2], sn[3]));
        const float l = nx - p + MARGIN;
        loss[row] = l > 0.f ? l : 0.f;
    }
}

// ---- mean over 1024 losses -> scalar ----
__global__ __launch_bounds__(256) void final_kernel(const float* __restrict__ loss,
                                                    float* __restrict__ out) {
    const int t = threadIdx.x;
    float s = loss[t] + loss[t + 256] + loss[t + 512] + loss[t + 768];
#pragma unroll
    for (int sh = 1; sh < 64; sh <<= 1) s += __shfl_xor(s, sh, 64);
    __shared__ float sb[4];
    if ((t & 63) == 0) sb[t >> 6] = s;
    __syncthreads();
    if (t == 0) out[0] = (sb[0] + sb[1] + sb[2] + sb[3]) * (1.0f / 1024.0f);
}

extern "C" void kernel_launch(void* const* d_in, const int* in_sizes, int n_in,
                              void* d_out, int out_size, void* d_ws, size_t ws_size,
                              hipStream_t stream) {
    const float* inputs = (const float*)d_in[0];     // [1024,512] f32
    const float* features = (const float*)d_in[1];   // [32768,512] f32
    const int* targets = (const int*)d_in[2];        // [1024] i32
    const int* idxv = (const int*)d_in[3];           // [1024] i32
    const int* labels = (const int*)d_in[4];         // [32768] i32

    char* ws = (char*)d_ws;
    ushort_t* A = (ushort_t*)ws;                               // 1 MB
    ushort_t* B = (ushort_t*)(ws + (1u << 20));                // 32 MB
    float* pos_part = (float*)(ws + (1u << 20) + (32u << 20)); // 2 MB
    float* neg_part = pos_part + (size_t)M * NPART;            // 2 MB
    float* loss = neg_part + (size_t)M * NPART;                // 4 KB

    // f32 -> bf16
    cvt_kernel<<<(NG * K / 8) / 256, 256, 0, stream>>>(features, B, NG * K / 8);
    cvt_kernel<<<(M * K / 8) / 256, 256, 0, stream>>>(inputs, A, M * K / 8);

    // fused GEMM + masked partial min/max
    gemm_kernel<<<(M / BM) * (NG / BN), 256, 0, stream>>>(A, B, targets, idxv, labels,
                                                          pos_part, neg_part);

    // per-row reduction + mean
    rowred_kernel<<<M, 256, 0, stream>>>(pos_part, neg_part, loss);
    final_kernel<<<1, 256, 0, stream>>>(loss, (float*)d_out);
}